// Round 1
// baseline (912.168 us; speedup 1.0000x reference)
//
#include <hip/hip_runtime.h>
#include <math.h>

#define NUM_SEQS   32
#define NUM_HEADS  16
#define HEAD_SIZE  128
#define BLOCK_SZ   16
#define MAX_BLOCKS 128
#define MAX_CTX    2048
#define ATTN_SCALE 0.08838834764831845f

// One 256-thread workgroup per (seq, head). Memory-bound: reads ctx*1KB per WG.
__global__ __launch_bounds__(256, 2)
void paged_attn_v1(const float* __restrict__ q,
                   const float* __restrict__ kcache,
                   const float* __restrict__ vcache,
                   const int*   __restrict__ btab,
                   const int*   __restrict__ ctxlen,
                   float*       __restrict__ out)
{
    const int sh  = blockIdx.x;
    const int s   = sh >> 4;     // / NUM_HEADS
    const int h   = sh & 15;
    const int tid = threadIdx.x;
    const int lane = tid & 63;
    const int wid  = tid >> 6;

    __shared__ float s_q[HEAD_SIZE];      // scaled query
    __shared__ float s_p[MAX_CTX];        // logits -> probabilities
    __shared__ int   s_bt[MAX_BLOCKS];    // this seq's block table row
    __shared__ float s_red[4];            // cross-wave reduction

    const int ctx  = ctxlen[s];
    const int nblk = (ctx + BLOCK_SZ - 1) / BLOCK_SZ;

    if (tid < 128) {
        s_q[tid]  = q[(s * NUM_HEADS + h) * HEAD_SIZE + tid] * ATTN_SCALE;
        s_bt[tid] = btab[s * MAX_BLOCKS + tid];
    }
    __syncthreads();

    // ---- Phase 1: logits. thread = (cache-block-local, token-in-block) ----
    // K slice per (pb,h): [d8=0..15][t=0..15][x=0..7], 2048 floats contiguous.
    {
        const int t   = tid & 15;
        const int cbl = tid >> 4;            // 0..15 cache blocks at a time
        for (int cb0 = 0; cb0 < nblk; cb0 += 16) {
            const int cb = cb0 + cbl;
            float logit = -INFINITY;
            if (cb < nblk) {
                const int pb = s_bt[cb];
                const float* kb = kcache + ((size_t)pb * NUM_HEADS + h) * 2048 + t * 8;
                float dot = 0.f;
                #pragma unroll
                for (int d8 = 0; d8 < 16; ++d8) {
                    float4 a = *(const float4*)(kb + d8 * 128);
                    float4 b = *(const float4*)(kb + d8 * 128 + 4);
                    dot += a.x * s_q[d8*8+0] + a.y * s_q[d8*8+1]
                         + a.z * s_q[d8*8+2] + a.w * s_q[d8*8+3]
                         + b.x * s_q[d8*8+4] + b.y * s_q[d8*8+5]
                         + b.z * s_q[d8*8+6] + b.w * s_q[d8*8+7];
                }
                const int tok = cb * BLOCK_SZ + t;
                logit = (tok < ctx) ? dot : -INFINITY;
            }
            s_p[(cb0 + cbl) * BLOCK_SZ + t] = logit;   // padded region gets -inf
        }
    }
    __syncthreads();

    const int L16 = nblk * BLOCK_SZ;   // padded-to-block context length

    // ---- Phase 2: softmax over s_p[0..L16) ----
    float m = -INFINITY;
    for (int i = tid; i < L16; i += 256) m = fmaxf(m, s_p[i]);
    #pragma unroll
    for (int off = 32; off; off >>= 1) m = fmaxf(m, __shfl_xor(m, off));
    if (lane == 0) s_red[wid] = m;
    __syncthreads();
    m = fmaxf(fmaxf(s_red[0], s_red[1]), fmaxf(s_red[2], s_red[3]));

    float sum = 0.f;
    for (int i = tid; i < L16; i += 256) {
        const float e = __expf(s_p[i] - m);   // exp(-inf)=0 masks padding
        s_p[i] = e;
        sum += e;
    }
    #pragma unroll
    for (int off = 32; off; off >>= 1) sum += __shfl_xor(sum, off);
    __syncthreads();                    // all reads of s_red done; s_p writes visible
    if (lane == 0) s_red[wid] = sum;
    __syncthreads();
    const float inv = 1.f / (s_red[0] + s_red[1] + s_red[2] + s_red[3]);

    // ---- Phase 3: out[d] = sum_t p[t] * v[d][t] ----
    // V slice per (pb,h): [d=0..127][t=0..15]. Thread i reads floats [i*8, i*8+8):
    // 256 threads cover the whole 8KB block contiguously.
    {
        const int d    = tid >> 1;
        const int half = tid & 1;
        float acc = 0.f;
        #pragma unroll 4
        for (int cb = 0; cb < nblk; ++cb) {
            const int pb = s_bt[cb];
            const float* vb = vcache + ((size_t)pb * NUM_HEADS + h) * 2048
                            + d * BLOCK_SZ + half * 8;
            float4 a = *(const float4*)(vb);
            float4 b = *(const float4*)(vb + 4);
            const float* pp = &s_p[cb * BLOCK_SZ + half * 8];
            acc += a.x * pp[0] + a.y * pp[1] + a.z * pp[2] + a.w * pp[3]
                 + b.x * pp[4] + b.y * pp[5] + b.z * pp[6] + b.w * pp[7];
        }
        acc += __shfl_xor(acc, 1);      // combine the two halves of each d
        if (half == 0)
            out[(s * NUM_HEADS + h) * HEAD_SIZE + d] = acc * inv;
    }
}

extern "C" void kernel_launch(void* const* d_in, const int* in_sizes, int n_in,
                              void* d_out, int out_size, void* d_ws, size_t ws_size,
                              hipStream_t stream) {
    const float* q  = (const float*)d_in[0];
    const float* kc = (const float*)d_in[1];
    const float* vc = (const float*)d_in[2];
    const int*   bt = (const int*)d_in[3];
    const int*   cl = (const int*)d_in[4];
    float* out = (float*)d_out;

    paged_attn_v1<<<dim3(NUM_SEQS * NUM_HEADS), dim3(256), 0, stream>>>(
        q, kc, vc, bt, cl, out);
}